// Round 9
// baseline (624.697 us; speedup 1.0000x reference)
//
#include <hip/hip_runtime.h>
#include <cstdint>
#include <cstddef>

#define T_STEPS 1024
#define NBLK    256   // 512 batch / 2 per block; 1 block per CU

typedef __attribute__((ext_vector_type(8))) _Float16 half8;
typedef __attribute__((ext_vector_type(4))) _Float16 half4;
typedef __attribute__((ext_vector_type(4))) float    f32x4;

static __device__ __forceinline__ float sigm(float x) {
  return __builtin_amdgcn_rcpf(1.0f + __expf(-x));
}
static __device__ __forceinline__ float tanh_(float x) {
  return 1.0f - 2.0f * __builtin_amdgcn_rcpf(__expf(2.0f * x) + 1.0f);
}

static __device__ __forceinline__ half8 load8(const float* s) {
  float4 a = ((const float4*)s)[0];
  float4 b = ((const float4*)s)[1];
  half8 h;
  h[0] = (_Float16)a.x; h[1] = (_Float16)a.y; h[2] = (_Float16)a.z; h[3] = (_Float16)a.w;
  h[4] = (_Float16)b.x; h[5] = (_Float16)b.y; h[6] = (_Float16)b.z; h[7] = (_Float16)b.w;
  return h;
}
static __device__ __forceinline__ half8 zero8() {
  half8 h;
  #pragma unroll
  for (int j = 0; j < 8; ++j) h[j] = (_Float16)0.0f;
  return h;
}
static __device__ __forceinline__ half4 cvt4(float4 v) {
  half4 h; h[0] = (_Float16)v.x; h[1] = (_Float16)v.y; h[2] = (_Float16)v.z; h[3] = (_Float16)v.w;
  return h;
}

// lgkm-only workgroup barrier: drains LDS ops (producer->consumer visibility)
// but leaves global loads in flight across the barrier.
static __device__ __forceinline__ void barrier_lds() {
  __asm__ volatile("s_waitcnt lgkmcnt(0)\n\ts_barrier" ::: "memory");
}

// Grid 256 x 512 threads, batch rows {2b,2b+1} at MFMA A-rows 0 and 4 (D reg0:
// batch0 lanes 0-15, batch1 lanes 16-31). Waves 0-3: L1, 4-7: L2; wave owns all
// 4 gate types of 16 units; in-wave activations; ONE (lgkm-only) barrier/phase.
//
// R9 changes vs R8:
//  (1) Bank-disjoint state layout: hstate[buf][kstep][batch][32]h (batch stride
//      64B == banks 0-15 vs 16-31; kstep stride 128B) — the R6/R8 conflicts
//      (2.755e7) came from batch windows overlapping banks, not slot stride.
//      xwin uses the same [slot][batch][32] rule.
//  (2) x held in a 128-step LDS window (2x16KB), refilled every 128 phases
//      (loads issued at p%128==0, staged at p%128==64; they float across the
//      lgkm-only barriers). No per-phase x machinery.
//  (3) L2 skewed to step t=p-2: its h1-kstep MFMAs are PRE-ISSUED in phase
//      t+1 (h1_t stable then), only the h2 ksteps run post-barrier — softens
//      the post-barrier MFMA burst (28 -> 20 per SIMD), fills the act tail.
// MFMA layouts (m89/m120-verified): A[m=l&15][k=(l>>4)*8+j];
// B[k=(l>>4)*8+j][n=l&15]; D[row=(l>>4)*4+reg][col=l&15].
__global__ __launch_bounds__(512, 2) void lstm_fused(
    const float* __restrict__ x,
    const float* __restrict__ w_ih1, const float* __restrict__ w_hh1,
    const float* __restrict__ b_ih1, const float* __restrict__ b_hh1,
    const float* __restrict__ w_ih2, const float* __restrict__ w_hh2,
    const float* __restrict__ b_ih2, const float* __restrict__ b_hh2,
    const float* __restrict__ fc1_w, const float* __restrict__ fc1_b,
    const float* __restrict__ fc2_w, const float* __restrict__ fc2_b,
    const float* __restrict__ ln_g, const float* __restrict__ ln_b,
    float* __restrict__ out)
{
  // ks0 = h1[0:32), ks1 = h1[32:64), ks2 = h2[0:32), ks3 = h2[32:64)
  __shared__ __align__(16) _Float16 hstate[2][4][2][32];   // 1 KB
  __shared__ __align__(16) _Float16 xwin[2][128][2][32];   // 32 KB
  __shared__ __align__(16) float hfin[2][64];
  __shared__ __align__(16) float y1s[2][128];
  __shared__ __align__(16) float y2s[2][128];
  __shared__ float redmu[2], redrs[2];

  const int t   = threadIdx.x;
  const int b   = blockIdx.x;
  const int l   = t & 63;
  const int w   = t >> 6;       // wave 0..7
  const int ly  = w >> 2;       // 0=L1, 1=L2
  const int wq  = w & 3;        // unit group
  const int col = l & 15;
  const int q   = l >> 4;       // quad
  const int bm  = ((l & 15) >> 2) & 1;  // batch whose A-row this lane serves

  // ---- init: zero h-state (both buffers: 512 halves, one per thread) ----
  ((_Float16*)hstate)[t] = (_Float16)0.0f;

  // ---- x refill lane mapping (all 512 threads, 4 float4 each / window) ----
  int xls[4]; size_t xgs[4];
  #pragma unroll
  for (int j = 0; j < 4; ++j) {
    const int i = t + 512 * j;
    const int bt = i >> 10, rem = i & 1023, st = rem >> 3, f4 = rem & 7;
    xgs[j] = ((size_t)(2 * b + bt) * T_STEPS + st) * 32 + f4 * 4;
    xls[j] = st * 128 + bt * 64 + f4 * 8;
  }
  // initial window 0 (steps 0..127) -> xwin buf 0
  #pragma unroll
  for (int j = 0; j < 4; ++j) {
    const float4 v = *(const float4*)(x + xgs[j]);
    *(half4*)((char*)xwin + xls[j]) = cvt4(v);
  }

  // ---- stationary weights -> B fragments wb[tile=gate][kstep] ----
  half8 wb[4][4];
  {
    const int ko = q * 8;
    #pragma unroll
    for (int tt = 0; tt < 4; ++tt) {
      const int r = tt * 64 + wq * 16 + col;
      if (ly == 0) {
        wb[tt][0] = load8(w_ih1 + r * 32 + ko);        // x kstep
        wb[tt][1] = load8(w_hh1 + r * 64 + ko);        // h1 lo
        wb[tt][2] = load8(w_hh1 + r * 64 + 32 + ko);   // h1 hi
        wb[tt][3] = zero8();
      } else {
        wb[tt][0] = load8(w_ih2 + r * 64 + ko);        // h1 lo
        wb[tt][1] = load8(w_ih2 + r * 64 + 32 + ko);   // h1 hi
        wb[tt][2] = load8(w_hh2 + r * 64 + ko);        // h2 lo
        wb[tt][3] = load8(w_hh2 + r * 64 + 32 + ko);   // h2 hi
      }
    }
  }

  // ---- act-lane setup (lanes 0-31): unit u, batch = l>>4 ----
  const int u = wq * 16 + col;
  float bia[4];
  {
    const float* bi_ = ly ? b_ih2 : b_ih1;
    const float* bh_ = ly ? b_hh2 : b_hh1;
    #pragma unroll
    for (int k2 = 0; k2 < 4; ++k2) bia[k2] = bi_[k2 * 64 + u] + bh_[k2 * 64 + u];
  }
  const int abm = l >> 4;                         // act batch (lanes 0-31)
  // act h-write byte offset (within hstate, + wrb*512): kstep*128 + batch*64 + idx*2
  const int hwofs = (ly ? (2 + (u >> 5)) : (u >> 5)) * 128 + abm * 64 + (u & 31) * 2;

  const char* hsbase = (const char*)hstate + bm * 64 + q * 16;
  const char* xwbase = (const char*)xwin   + bm * 64 + q * 16;

  __syncthreads();

  // carried accumulator (L1: x-kstep pre-issue; L2: h1-kstep pre-issue)
  f32x4 accp[4];
  #pragma unroll
  for (int tt = 0; tt < 4; ++tt) accp[tt] = (f32x4){0.f, 0.f, 0.f, 0.f};
  if (ly == 0) {
    const half8 ax = *(const half8*)xwbase;   // buf0 slot0 = x_0
    #pragma unroll
    for (int tt = 0; tt < 4; ++tt)
      accp[tt] = __builtin_amdgcn_mfma_f32_16x16x32_f16(ax, wb[tt][0], accp[tt], 0, 0, 0);
  }

  float4 xv[4];
  #pragma unroll
  for (int j = 0; j < 4; ++j) xv[j] = make_float4(0.f, 0.f, 0.f, 0.f);
  float c = 0.0f;

  for (int p = 0; p <= T_STEPS + 1; ++p) {
    const int rd  = (p + 1) & 1;   // state buffer holding phase-(p-1) outputs
    const int wrb = p & 1;
    const int pw  = p & 127;
    const int nw  = (p >> 7) + 1;  // next x window index

    // issue next-window global loads (consumed at pw==64; float across barriers)
    if (pw == 0 && nw < 8) {
      const size_t base = (size_t)nw * 128 * 32;
      #pragma unroll
      for (int j = 0; j < 4; ++j) xv[j] = *(const float4*)(x + xgs[j] + base);
    }

    if (ly == 0) {
      // ---- L1, step t=p ----
      if (p < T_STEPS) {
        const char* hb = hsbase + rd * 512;
        const half8 a1 = *(const half8*)(hb);         // ks0: h1 lo
        const half8 a2 = *(const half8*)(hb + 128);   // ks1: h1 hi
        f32x4 acc[4];
        #pragma unroll
        for (int tt = 0; tt < 4; ++tt) {
          acc[tt] = __builtin_amdgcn_mfma_f32_16x16x32_f16(a1, wb[tt][1], accp[tt], 0, 0, 0);
          acc[tt] = __builtin_amdgcn_mfma_f32_16x16x32_f16(a2, wb[tt][2], acc[tt], 0, 0, 0);
        }
        if (l < 32) {
          const float gi = sigm(acc[0][0] + bia[0]);
          const float gf = sigm(acc[1][0] + bia[1]);
          const float gg = tanh_(acc[2][0] + bia[2]);
          const float go = sigm(acc[3][0] + bia[3]);
          c = gf * c + gi * gg;
          const float hv = go * tanh_(c);
          *(_Float16*)((char*)hstate + wrb * 512 + hwofs) = (_Float16)hv;
        }
        // pre-issue x-ksteps for step p+1
        if (p + 1 < T_STEPS) {
          const int pn = p + 1;
          const half8 ax = *(const half8*)(xwbase + ((pn >> 7) & 1) * 16384 + (pn & 127) * 128);
          #pragma unroll
          for (int tt = 0; tt < 4; ++tt)
            accp[tt] = __builtin_amdgcn_mfma_f32_16x16x32_f16(ax, wb[tt][0], (f32x4){0.f,0.f,0.f,0.f}, 0, 0, 0);
        }
      }
    } else {
      // ---- L2, step t=p-2 (h1 ksteps pre-issued last phase) ----
      if (p >= 2) {
        const char* hb = hsbase + rd * 512;
        const half8 a2lo = *(const half8*)(hb + 256);   // ks2: h2 lo
        const half8 a2hi = *(const half8*)(hb + 384);   // ks3: h2 hi
        f32x4 acc[4];
        #pragma unroll
        for (int tt = 0; tt < 4; ++tt) {
          acc[tt] = __builtin_amdgcn_mfma_f32_16x16x32_f16(a2lo, wb[tt][2], accp[tt], 0, 0, 0);
          acc[tt] = __builtin_amdgcn_mfma_f32_16x16x32_f16(a2hi, wb[tt][3], acc[tt], 0, 0, 0);
        }
        if (l < 32) {
          const float gi = sigm(acc[0][0] + bia[0]);
          const float gf = sigm(acc[1][0] + bia[1]);
          const float gg = tanh_(acc[2][0] + bia[2]);
          const float go = sigm(acc[3][0] + bia[3]);
          c = gf * c + gi * gg;
          const float hv = go * tanh_(c);
          *(_Float16*)((char*)hstate + wrb * 512 + hwofs) = (_Float16)hv;
          if (p == T_STEPS + 1) hfin[abm][u] = hv;   // h2_{T-1}
        }
      }
      // pre-issue h1-ksteps for step p-1 (h1_{p-1} is in buf rd, stable)
      if (p >= 1 && p <= T_STEPS) {
        const char* hb1 = hsbase + rd * 512;
        const half8 b1lo = *(const half8*)(hb1);         // ks0
        const half8 b1hi = *(const half8*)(hb1 + 128);   // ks1
        #pragma unroll
        for (int tt = 0; tt < 4; ++tt) {
          accp[tt] = __builtin_amdgcn_mfma_f32_16x16x32_f16(b1lo, wb[tt][0], (f32x4){0.f,0.f,0.f,0.f}, 0, 0, 0);
          accp[tt] = __builtin_amdgcn_mfma_f32_16x16x32_f16(b1hi, wb[tt][1], accp[tt], 0, 0, 0);
        }
      }
    }

    // stage the register-held x window (loaded 64 phases ago)
    if (pw == 64 && nw < 8) {
      const int wb2 = nw & 1;
      #pragma unroll
      for (int j = 0; j < 4; ++j)
        *(half4*)((char*)xwin + wb2 * 16384 + xls[j]) = cvt4(xv[j]);
    }
    barrier_lds();
  }

  __syncthreads();   // full drain before epilogue

  // ---- head: y = LN(relu(hT@fc1^T+b1)@fc2^T+b2), 2 batch rows ----
  if (t < 256) {
    const int bi = t >> 7, j = t & 127;
    float a = fc1_b[j];
    const float4* w4 = (const float4*)(fc1_w + j * 64);
    const float4* h4 = (const float4*)hfin[bi];
    #pragma unroll
    for (int qq = 0; qq < 16; ++qq) {
      float4 wv = w4[qq]; float4 hv = h4[qq];
      a += wv.x * hv.x + wv.y * hv.y + wv.z * hv.z + wv.w * hv.w;
    }
    y1s[bi][j] = fmaxf(a, 0.0f);
  }
  __syncthreads();
  if (t < 256) {
    const int bi = t >> 7, j = t & 127;
    float a = fc2_b[j];
    const float4* w4 = (const float4*)(fc2_w + j * 128);
    const float4* y4 = (const float4*)y1s[bi];
    #pragma unroll
    for (int qq = 0; qq < 32; ++qq) {
      float4 wv = w4[qq]; float4 yv = y4[qq];
      a += wv.x * yv.x + wv.y * yv.y + wv.z * yv.z + wv.w * yv.w;
    }
    y2s[bi][j] = a;
  }
  __syncthreads();
  if (t < 128) {
    const int bi = t >> 6, jj = t & 63;
    float s  = y2s[bi][jj] + y2s[bi][64 + jj];
    float qs = y2s[bi][jj] * y2s[bi][jj] + y2s[bi][64 + jj] * y2s[bi][64 + jj];
    #pragma unroll
    for (int off = 32; off > 0; off >>= 1) {
      s  += __shfl_down(s, off, 64);
      qs += __shfl_down(qs, off, 64);
    }
    if (jj == 0) {
      const float mu  = s * (1.0f / 128.0f);
      const float var = qs * (1.0f / 128.0f) - mu * mu;
      redmu[bi] = mu;
      redrs[bi] = rsqrtf(var + 1e-5f);
    }
  }
  __syncthreads();
  if (t < 256) {
    const int bi = t >> 7, j = t & 127;
    out[(size_t)(2 * b + bi) * 128 + j] =
        (y2s[bi][j] - redmu[bi]) * redrs[bi] * ln_g[j] + ln_b[j];
  }
}

extern "C" void kernel_launch(void* const* d_in, const int* in_sizes, int n_in,
                              void* d_out, int out_size, void* d_ws, size_t ws_size,
                              hipStream_t stream) {
  const float* x     = (const float*)d_in[0];
  const float* w_ih1 = (const float*)d_in[1];
  const float* w_hh1 = (const float*)d_in[2];
  const float* b_ih1 = (const float*)d_in[3];
  const float* b_hh1 = (const float*)d_in[4];
  const float* w_ih2 = (const float*)d_in[5];
  const float* w_hh2 = (const float*)d_in[6];
  const float* b_ih2 = (const float*)d_in[7];
  const float* b_hh2 = (const float*)d_in[8];
  const float* fc1_w = (const float*)d_in[9];
  const float* fc1_b = (const float*)d_in[10];
  const float* fc2_w = (const float*)d_in[11];
  const float* fc2_b = (const float*)d_in[12];
  const float* ln_g  = (const float*)d_in[13];
  const float* ln_b  = (const float*)d_in[14];
  float* out = (float*)d_out;

  lstm_fused<<<NBLK, 512, 0, stream>>>(x, w_ih1, w_hh1, b_ih1, b_hh1,
                                       w_ih2, w_hh2, b_ih2, b_hh2,
                                       fc1_w, fc1_b, fc2_w, fc2_b,
                                       ln_g, ln_b, out);
}

// Round 10
// 595.890 us; speedup vs baseline: 1.0483x; 1.0483x over previous
//
#include <hip/hip_runtime.h>
#include <cstdint>
#include <cstddef>

#define T_STEPS 1024
#define NBLK    256   // 512 batch / 2 per block; 1 block per CU
#define LOG2E   1.4426950408889634f

typedef __attribute__((ext_vector_type(8))) _Float16 half8;
typedef __attribute__((ext_vector_type(4))) _Float16 half4;
typedef __attribute__((ext_vector_type(4))) float    f32x4;

static __device__ __forceinline__ float fexp2(float x) {
#if defined(__has_builtin) && __has_builtin(__builtin_amdgcn_exp2f)
  return __builtin_amdgcn_exp2f(x);
#else
  return __exp2f(x);
#endif
}
// pre-acts arrive PRE-SCALED by log2e (weights/bias scaled at load)
static __device__ __forceinline__ float sigm2(float a) {          // sigmoid(a/log2e)
  return __builtin_amdgcn_rcpf(1.0f + fexp2(-a));
}
static __device__ __forceinline__ float tanhg2(float a) {         // tanh(a/log2e)
  return 2.0f * __builtin_amdgcn_rcpf(1.0f + fexp2(-(a + a))) - 1.0f;
}
static __device__ __forceinline__ float tanhc(float c) {          // tanh(c), c unscaled
  return 1.0f - 2.0f * __builtin_amdgcn_rcpf(1.0f + fexp2(c * (2.0f * LOG2E)));
}

static __device__ __forceinline__ half8 load8s(const float* s, float sc) {
  float4 a = ((const float4*)s)[0];
  float4 b = ((const float4*)s)[1];
  half8 h;
  h[0] = (_Float16)(a.x * sc); h[1] = (_Float16)(a.y * sc);
  h[2] = (_Float16)(a.z * sc); h[3] = (_Float16)(a.w * sc);
  h[4] = (_Float16)(b.x * sc); h[5] = (_Float16)(b.y * sc);
  h[6] = (_Float16)(b.z * sc); h[7] = (_Float16)(b.w * sc);
  return h;
}
static __device__ __forceinline__ half8 zero8() {
  half8 h;
  #pragma unroll
  for (int j = 0; j < 8; ++j) h[j] = (_Float16)0.0f;
  return h;
}
static __device__ __forceinline__ half4 cvt4(float4 v) {
  half4 h; h[0] = (_Float16)v.x; h[1] = (_Float16)v.y; h[2] = (_Float16)v.z; h[3] = (_Float16)v.w;
  return h;
}

// lgkm-only workgroup barrier: drains LDS ops (producer->consumer visibility)
// but leaves global loads in flight across the barrier.
static __device__ __forceinline__ void barrier_lds() {
  __asm__ volatile("s_waitcnt lgkmcnt(0)\n\ts_barrier" ::: "memory");
}

// R10 = R8 schedule (best: 552us best-dispatch) + verified fixes:
//  (1) bank-disjoint hstate[buf][kstep][batch][32] (R9-verified: conflicts
//      2.755e7 -> 2.6e5; batch stride 64B = banks 0-15 vs 16-31).
//  (2) R6-style xbig[2][16][2][32] (slot 128B, batch 64B - already disjoint);
//      L2 skew and 128-step window REVERTED (R9 net regression).
//  (3) bias folded into MFMA C-init (removes 4 VALU adds from the act chain).
//  (4) weights/biases pre-scaled by log2e -> acts use native v_exp_f32 (2^x)
//      without per-gate multiplies.
// Grid 256 x 512 threads, batch {2b,2b+1} at MFMA A-rows 0,4 (D reg0: batch0
// lanes 0-15, batch1 lanes 16-31). Waves 0-3: L1, 4-7: L2; wave owns all 4
// gate types of 16 units; in-wave acts; ONE lgkm-only barrier/phase; L1
// pre-reads x-frag and pre-issues x-kstep MFMAs before the barrier.
// MFMA layouts (m89/m120-verified): A[m=l&15][k=(l>>4)*8+j];
// B[k=(l>>4)*8+j][n=l&15]; D[row=(l>>4)*4+reg][col=l&15].
__global__ __launch_bounds__(512, 2) void lstm_fused(
    const float* __restrict__ x,
    const float* __restrict__ w_ih1, const float* __restrict__ w_hh1,
    const float* __restrict__ b_ih1, const float* __restrict__ b_hh1,
    const float* __restrict__ w_ih2, const float* __restrict__ w_hh2,
    const float* __restrict__ b_ih2, const float* __restrict__ b_hh2,
    const float* __restrict__ fc1_w, const float* __restrict__ fc1_b,
    const float* __restrict__ fc2_w, const float* __restrict__ fc2_b,
    const float* __restrict__ ln_g, const float* __restrict__ ln_b,
    float* __restrict__ out)
{
  // ks0 = h1[0:32), ks1 = h1[32:64), ks2 = h2[0:32), ks3 = h2[32:64)
  __shared__ __align__(16) _Float16 hstate[2][4][2][32];   // 1 KB, bank-disjoint
  __shared__ __align__(16) _Float16 xbig[2][16][2][32];    // 4 KB
  __shared__ __align__(16) float hfin[2][64];
  __shared__ __align__(16) float y1s[2][128];
  __shared__ __align__(16) float y2s[2][128];
  __shared__ float redmu[2], redrs[2];

  const int t   = threadIdx.x;
  const int b   = blockIdx.x;
  const int l   = t & 63;
  const int w   = t >> 6;       // wave 0..7
  const int ly  = w >> 2;       // 0=L1, 1=L2
  const int wq  = w & 3;        // unit group
  const int col = l & 15;
  const int q   = l >> 4;       // quad
  const int bm  = ((l & 15) >> 2) & 1;  // batch whose A-row this lane serves

  // ---- init: zero h-state (both buffers: 512 halves, one per thread) ----
  ((_Float16*)hstate)[t] = (_Float16)0.0f;

  // ---- init: preload x[0..16) into xbig buf0 ----
  if (t < 256) {
    const int b0 = t >> 7, r0 = t & 127, tr0 = r0 >> 3, ii0 = r0 & 7;
    const float4 v = *(const float4*)(x + ((size_t)(2 * b + b0) * T_STEPS + tr0) * 32 + ii0 * 4);
    *(half4*)((char*)xbig + tr0 * 128 + b0 * 64 + ii0 * 8) = cvt4(v);
  }

  // ---- stationary weights (pre-scaled by log2e) -> B frags wb[tile][kstep] ----
  half8 wb[4][4];
  {
    const int ko = q * 8;
    #pragma unroll
    for (int tt = 0; tt < 4; ++tt) {
      const int r = tt * 64 + wq * 16 + col;
      if (ly == 0) {
        wb[tt][0] = load8s(w_ih1 + r * 32 + ko, LOG2E);        // x kstep
        wb[tt][1] = load8s(w_hh1 + r * 64 + ko, LOG2E);        // h1 lo
        wb[tt][2] = load8s(w_hh1 + r * 64 + 32 + ko, LOG2E);   // h1 hi
        wb[tt][3] = zero8();
      } else {
        wb[tt][0] = load8s(w_ih2 + r * 64 + ko, LOG2E);        // h1 lo
        wb[tt][1] = load8s(w_ih2 + r * 64 + 32 + ko, LOG2E);   // h1 hi
        wb[tt][2] = load8s(w_hh2 + r * 64 + ko, LOG2E);        // h2 lo
        wb[tt][3] = load8s(w_hh2 + r * 64 + 32 + ko, LOG2E);   // h2 hi
      }
    }
  }

  // ---- per-tile bias (scaled by log2e), used as MFMA C-init ----
  float bia[4];
  {
    const float* bi_ = ly ? b_ih2 : b_ih1;
    const float* bh_ = ly ? b_hh2 : b_hh1;
    #pragma unroll
    for (int tt = 0; tt < 4; ++tt) {
      const int r = tt * 64 + wq * 16 + col;    // this lane's own gate row
      bia[tt] = (bi_[r] + bh_[r]) * LOG2E;
    }
  }
  // act-lane mapping (lanes 0-31): unit u, batch = l>>4
  const int u   = wq * 16 + col;
  const int abm = l >> 4;
  const int hwofs = (ly ? (2 + (u >> 5)) : (u >> 5)) * 128 + abm * 64 + (u & 31) * 2;

  // ---- bulk x-prefetch lane mapping (lanes 32-63, all 8 waves = 256 lanes) ----
  const bool isx = (l >= 32);
  const int g   = w * 32 + (l - 32);      // 0..255
  const int xbm = g >> 7, xr = g & 127, xtr = xr >> 3, xii = xr & 7;
  const float* xsrc = x + ((size_t)(2 * b + xbm) * T_STEPS) * 32 + xii * 4;

  const char* hsbase = (const char*)hstate + bm * 64 + q * 16;  // + buf*512 + ks*128
  const char* xwbase = (const char*)xbig   + bm * 64 + q * 16;  // + buf*2048 + slot*128

  __syncthreads();

  // ---- pre-issue phase-0 x-kstep MFMAs (L1), C = bias ----
  f32x4 accp[4];
  #pragma unroll
  for (int tt = 0; tt < 4; ++tt) accp[tt] = (f32x4){bia[tt], bia[tt], bia[tt], bia[tt]};
  if (ly == 0) {
    const half8 ax = *(const half8*)xwbase;   // buf0 slot0 = x_0
    #pragma unroll
    for (int tt = 0; tt < 4; ++tt)
      accp[tt] = __builtin_amdgcn_mfma_f32_16x16x32_f16(ax, wb[tt][0], accp[tt], 0, 0, 0);
  }

  float4 xv = make_float4(0.f, 0.f, 0.f, 0.f);
  float c = 0.0f;

  for (int p = 0; p <= T_STEPS; ++p) {
    const int rd  = (p + 1) & 1;
    const int wrb = p & 1;

    // issue bulk x loads (consumed at p%16==8; float across lgkm-only barriers)
    if (isx && (p & 15) == 0 && (p + 16 + xtr) < T_STEPS)
      xv = *(const float4*)(xsrc + (size_t)(p + 16 + xtr) * 32);

    // ---- h-fragments + chained MFMAs ----
    const char* hb = hsbase + rd * 512;
    f32x4 acc[4];
    if (ly == 0) {
      const half8 a1 = *(const half8*)(hb);         // ks0: h1 lo
      const half8 a2 = *(const half8*)(hb + 128);   // ks1: h1 hi
      #pragma unroll
      for (int tt = 0; tt < 4; ++tt) {
        acc[tt] = __builtin_amdgcn_mfma_f32_16x16x32_f16(a1, wb[tt][1], accp[tt], 0, 0, 0);
        acc[tt] = __builtin_amdgcn_mfma_f32_16x16x32_f16(a2, wb[tt][2], acc[tt], 0, 0, 0);
      }
    } else {
      const half8 a0 = *(const half8*)(hb);         // ks0: h1 lo
      const half8 a1 = *(const half8*)(hb + 128);   // ks1: h1 hi
      const half8 a2 = *(const half8*)(hb + 256);   // ks2: h2 lo
      const half8 a3 = *(const half8*)(hb + 384);   // ks3: h2 hi
      #pragma unroll
      for (int tt = 0; tt < 4; ++tt) {
        f32x4 a = __builtin_amdgcn_mfma_f32_16x16x32_f16(a0, wb[tt][0],
                    (f32x4){bia[tt], bia[tt], bia[tt], bia[tt]}, 0, 0, 0);
        a = __builtin_amdgcn_mfma_f32_16x16x32_f16(a1, wb[tt][1], a, 0, 0, 0);
        a = __builtin_amdgcn_mfma_f32_16x16x32_f16(a2, wb[tt][2], a, 0, 0, 0);
        acc[tt] = __builtin_amdgcn_mfma_f32_16x16x32_f16(a3, wb[tt][3], a, 0, 0, 0);
      }
    }

    // ---- in-wave activations: lanes 0-31 (bias already inside acc) ----
    if (l < 32 && (ly == 0 || p > 0)) {
      const float gi = sigm2 (acc[0][0]);
      const float gf = sigm2 (acc[1][0]);
      const float gg = tanhg2(acc[2][0]);
      const float go = sigm2 (acc[3][0]);
      c = gf * c + gi * gg;
      const float hv = go * tanhc(c);
      *(_Float16*)((char*)hstate + wrb * 512 + hwofs) = (_Float16)hv;
      if (ly == 1 && p == T_STEPS) hfin[abm][u] = hv;   // h2_{T-1}
    }

    // ---- pre-read next x-frag + pre-issue x-kstep MFMAs (L1), C = bias ----
    if (ly == 0 && p < T_STEPS) {
      const int pn = p + 1;
      const half8 ax = *(const half8*)(xwbase + ((pn >> 4) & 1) * 2048 + (pn & 15) * 128);
      #pragma unroll
      for (int tt = 0; tt < 4; ++tt)
        accp[tt] = __builtin_amdgcn_mfma_f32_16x16x32_f16(ax, wb[tt][0],
                     (f32x4){bia[tt], bia[tt], bia[tt], bia[tt]}, 0, 0, 0);
    }

    // ---- stage the register-held x window (loaded 8 phases ago) ----
    if (isx && (p & 15) == 8 && (p + 8 + xtr) < T_STEPS)
      *(half4*)((char*)xbig + (((p >> 4) + 1) & 1) * 2048 + xtr * 128 + xbm * 64 + xii * 8) = cvt4(xv);

    barrier_lds();
  }

  __syncthreads();   // full drain before epilogue

  // ---- head: y = LN(relu(hT@fc1^T+b1)@fc2^T+b2), 2 batch rows ----
  if (t < 256) {
    const int bi = t >> 7, j = t & 127;
    float a = fc1_b[j];
    const float4* w4 = (const float4*)(fc1_w + j * 64);
    const float4* h4 = (const float4*)hfin[bi];
    #pragma unroll
    for (int qq = 0; qq < 16; ++qq) {
      float4 wv = w4[qq]; float4 hv = h4[qq];
      a += wv.x * hv.x + wv.y * hv.y + wv.z * hv.z + wv.w * hv.w;
    }
    y1s[bi][j] = fmaxf(a, 0.0f);
  }
  __syncthreads();
  if (t < 256) {
    const int bi = t >> 7, j = t & 127;
    float a = fc2_b[j];
    const float4* w4 = (const float4*)(fc2_w + j * 128);
    const float4* y4 = (const float4*)y1s[bi];
    #pragma unroll
    for (int qq = 0; qq < 32; ++qq) {
      float4 wv = w4[qq]; float4 yv = y4[qq];
      a += wv.x * yv.x + wv.y * yv.y + wv.z * yv.z + wv.w * yv.w;
    }
    y2s[bi][j] = a;
  }
  __syncthreads();
  if (t < 128) {
    const int bi = t >> 6, jj = t & 63;
    float s  = y2s[bi][jj] + y2s[bi][64 + jj];
    float qs = y2s[bi][jj] * y2s[bi][jj] + y2s[bi][64 + jj] * y2s[bi][64 + jj];
    #pragma unroll
    for (int off = 32; off > 0; off >>= 1) {
      s  += __shfl_down(s, off, 64);
      qs += __shfl_down(qs, off, 64);
    }
    if (jj == 0) {
      const float mu  = s * (1.0f / 128.0f);
      const float var = qs * (1.0f / 128.0f) - mu * mu;
      redmu[bi] = mu;
      redrs[bi] = rsqrtf(var + 1e-5f);
    }
  }
  __syncthreads();
  if (t < 256) {
    const int bi = t >> 7, j = t & 127;
    out[(size_t)(2 * b + bi) * 128 + j] =
        (y2s[bi][j] - redmu[bi]) * redrs[bi] * ln_g[j] + ln_b[j];
  }
}

extern "C" void kernel_launch(void* const* d_in, const int* in_sizes, int n_in,
                              void* d_out, int out_size, void* d_ws, size_t ws_size,
                              hipStream_t stream) {
  const float* x     = (const float*)d_in[0];
  const float* w_ih1 = (const float*)d_in[1];
  const float* w_hh1 = (const float*)d_in[2];
  const float* b_ih1 = (const float*)d_in[3];
  const float* b_hh1 = (const float*)d_in[4];
  const float* w_ih2 = (const float*)d_in[5];
  const float* w_hh2 = (const float*)d_in[6];
  const float* b_ih2 = (const float*)d_in[7];
  const float* b_hh2 = (const float*)d_in[8];
  const float* fc1_w = (const float*)d_in[9];
  const float* fc1_b = (const float*)d_in[10];
  const float* fc2_w = (const float*)d_in[11];
  const float* fc2_b = (const float*)d_in[12];
  const float* ln_g  = (const float*)d_in[13];
  const float* ln_b  = (const float*)d_in[14];
  float* out = (float*)d_out;

  lstm_fused<<<NBLK, 512, 0, stream>>>(x, w_ih1, w_hh1, b_ih1, b_hh1,
                                       w_ih2, w_hh2, b_ih2, b_hh2,
                                       fc1_w, fc1_b, fc2_w, fc2_b,
                                       ln_g, ln_b, out);
}

// Round 11
// 542.617 us; speedup vs baseline: 1.1513x; 1.0982x over previous
//
#include <hip/hip_runtime.h>
#include <cstdint>
#include <cstddef>

#define T_STEPS 1024
#define NBLK    256   // 512 batch / 2 per block; 1 block per CU
#define LOG2E   1.4426950408889634f

typedef __attribute__((ext_vector_type(8))) _Float16 half8;
typedef __attribute__((ext_vector_type(4))) _Float16 half4;
typedef __attribute__((ext_vector_type(4))) float    f32x4;

static __device__ __forceinline__ float fexp2(float x) {
#if defined(__has_builtin) && __has_builtin(__builtin_amdgcn_exp2f)
  return __builtin_amdgcn_exp2f(x);
#else
  return __exp2f(x);
#endif
}
// pre-acts arrive PRE-SCALED by log2e (weights/bias scaled at load)
static __device__ __forceinline__ float sigm2(float a) {          // sigmoid(a/log2e)
  return __builtin_amdgcn_rcpf(1.0f + fexp2(-a));
}
static __device__ __forceinline__ float tanhg2(float a) {         // tanh(a/log2e)
  return 2.0f * __builtin_amdgcn_rcpf(1.0f + fexp2(-(a + a))) - 1.0f;
}
static __device__ __forceinline__ float tanhc(float c) {          // tanh(c), c unscaled
  return 1.0f - 2.0f * __builtin_amdgcn_rcpf(1.0f + fexp2(c * (2.0f * LOG2E)));
}

static __device__ __forceinline__ half8 load8s(const float* s, float sc) {
  float4 a = ((const float4*)s)[0];
  float4 b = ((const float4*)s)[1];
  half8 h;
  h[0] = (_Float16)(a.x * sc); h[1] = (_Float16)(a.y * sc);
  h[2] = (_Float16)(a.z * sc); h[3] = (_Float16)(a.w * sc);
  h[4] = (_Float16)(b.x * sc); h[5] = (_Float16)(b.y * sc);
  h[6] = (_Float16)(b.z * sc); h[7] = (_Float16)(b.w * sc);
  return h;
}
static __device__ __forceinline__ half4 cvt4(float4 v) {
  half4 h; h[0] = (_Float16)v.x; h[1] = (_Float16)v.y; h[2] = (_Float16)v.z; h[3] = (_Float16)v.w;
  return h;
}

// lgkm-only workgroup barrier: drains LDS ops (producer->consumer visibility)
// but leaves global loads in flight across the barrier.
static __device__ __forceinline__ void barrier_lds() {
  __asm__ volatile("s_waitcnt lgkmcnt(0)\n\ts_barrier" ::: "memory");
}

// R11 = R10 + critical-path restructure:
//  (1) L2 skewed to step t=p-2. Post-barrier, L2 reads ONLY the h2 frags and
//      issues 8 MFMAs to finish step p-2 (the h1 ksteps were issued LAST phase
//      into the carried accumulator accq) -> acts start after 8 MFMAs, not 16.
//      The h1-kstep read+issue for step p-1 runs MID-phase (h1_{p-1} is stable
//      the whole phase), overlapping act VALU; nothing is appended after acts
//      (R9's end-of-phase placement extended the drain -> regressed).
//  (2) L1's next-x read + accp pre-issue moved BEFORE acts (was after).
//  (3) phase loop unrolled x2: buffer offsets are compile-time per half.
// Buffering: writes at phase p -> buf p&1; all reads at phase p -> buf (p+1)&1.
// Grid 256 x 512 threads, batch {2b,2b+1} at MFMA A-rows 0,4. Waves 0-3: L1,
// 4-7: L2; wave owns all 4 gate types of 16 units; in-wave acts; ONE lgkm-only
// barrier/phase; bank-disjoint hstate[buf][kstep][batch][32] (R9-verified);
// bias folded into MFMA C-init; log2e pre-scale -> native v_exp_f32 acts.
// MFMA layouts (m89/m120-verified): A[m=l&15][k=(l>>4)*8+j];
// B[k=(l>>4)*8+j][n=l&15]; D[row=(l>>4)*4+reg][col=l&15].
__global__ __launch_bounds__(512, 2) void lstm_fused(
    const float* __restrict__ x,
    const float* __restrict__ w_ih1, const float* __restrict__ w_hh1,
    const float* __restrict__ b_ih1, const float* __restrict__ b_hh1,
    const float* __restrict__ w_ih2, const float* __restrict__ w_hh2,
    const float* __restrict__ b_ih2, const float* __restrict__ b_hh2,
    const float* __restrict__ fc1_w, const float* __restrict__ fc1_b,
    const float* __restrict__ fc2_w, const float* __restrict__ fc2_b,
    const float* __restrict__ ln_g, const float* __restrict__ ln_b,
    float* __restrict__ out)
{
  // ks0 = h1[0:32), ks1 = h1[32:64), ks2 = h2[0:32), ks3 = h2[32:64)
  __shared__ __align__(16) _Float16 hstate[2][4][2][32];   // 1 KB, bank-disjoint
  __shared__ __align__(16) _Float16 xbig[2][16][2][32];    // 4 KB
  __shared__ __align__(16) float hfin[2][64];
  __shared__ __align__(16) float y1s[2][128];
  __shared__ __align__(16) float y2s[2][128];
  __shared__ float redmu[2], redrs[2];

  const int t   = threadIdx.x;
  const int b   = blockIdx.x;
  const int l   = t & 63;
  const int w   = t >> 6;       // wave 0..7
  const int ly  = w >> 2;       // 0=L1, 1=L2
  const int wq  = w & 3;        // unit group
  const int col = l & 15;
  const int q   = l >> 4;       // quad
  const int bm  = ((l & 15) >> 2) & 1;  // batch whose A-row this lane serves

  // ---- init: zero h-state (both buffers: 512 halves, one per thread) ----
  ((_Float16*)hstate)[t] = (_Float16)0.0f;

  // ---- init: preload x[0..16) into xbig buf0 ----
  if (t < 256) {
    const int b0 = t >> 7, r0 = t & 127, tr0 = r0 >> 3, ii0 = r0 & 7;
    const float4 v = *(const float4*)(x + ((size_t)(2 * b + b0) * T_STEPS + tr0) * 32 + ii0 * 4);
    *(half4*)((char*)xbig + tr0 * 128 + b0 * 64 + ii0 * 8) = cvt4(v);
  }

  // ---- stationary weights (pre-scaled by log2e) -> B frags wb[tile][kstep] ----
  half8 wb[4][4];
  {
    const int ko = q * 8;
    #pragma unroll
    for (int tt = 0; tt < 4; ++tt) {
      const int r = tt * 64 + wq * 16 + col;
      if (ly == 0) {
        wb[tt][0] = load8s(w_ih1 + r * 32 + ko, LOG2E);        // x kstep
        wb[tt][1] = load8s(w_hh1 + r * 64 + ko, LOG2E);        // h1 lo
        wb[tt][2] = load8s(w_hh1 + r * 64 + 32 + ko, LOG2E);   // h1 hi
        wb[tt][3] = wb[tt][0];                                 // unused
      } else {
        wb[tt][0] = load8s(w_ih2 + r * 64 + ko, LOG2E);        // h1 lo
        wb[tt][1] = load8s(w_ih2 + r * 64 + 32 + ko, LOG2E);   // h1 hi
        wb[tt][2] = load8s(w_hh2 + r * 64 + ko, LOG2E);        // h2 lo
        wb[tt][3] = load8s(w_hh2 + r * 64 + 32 + ko, LOG2E);   // h2 hi
      }
    }
  }

  // ---- per-tile bias (scaled by log2e), used as MFMA C-init ----
  float bia[4];
  {
    const float* bi_ = ly ? b_ih2 : b_ih1;
    const float* bh_ = ly ? b_hh2 : b_hh1;
    #pragma unroll
    for (int tt = 0; tt < 4; ++tt) {
      const int r = tt * 64 + wq * 16 + col;
      bia[tt] = (bi_[r] + bh_[r]) * LOG2E;
    }
  }
  // act-lane mapping (lanes 0-31): unit u, batch = l>>4
  const int u   = wq * 16 + col;
  const int abm = l >> 4;
  const int hwofs = (ly ? (2 + (u >> 5)) : (u >> 5)) * 128 + abm * 64 + (u & 31) * 2;

  // ---- bulk x-prefetch lane mapping (lanes 32-63, all 8 waves = 256 lanes) ----
  const bool isx = (l >= 32);
  const int g   = w * 32 + (l - 32);      // 0..255
  const int xbm = g >> 7, xr = g & 127, xtr = xr >> 3, xii = xr & 7;
  const float* xsrc = x + ((size_t)(2 * b + xbm) * T_STEPS) * 32 + xii * 4;

  const char* hsbase = (const char*)hstate + bm * 64 + q * 16;  // + buf*512 + ks*128
  const char* xwbase = (const char*)xbig   + bm * 64 + q * 16;  // + buf*2048 + slot*128

  __syncthreads();

  // ---- pre-issue phase-0 x-kstep MFMAs (L1 step 0), C = bias ----
  f32x4 accp[4];   // L1 carried: x-ksteps of step p+1
  f32x4 accq[4];   // L2 carried: h1-ksteps of step p-1
  #pragma unroll
  for (int tt = 0; tt < 4; ++tt) {
    accp[tt] = (f32x4){bia[tt], bia[tt], bia[tt], bia[tt]};
    accq[tt] = accp[tt];
  }
  if (ly == 0) {
    const half8 ax = *(const half8*)xwbase;   // buf0 slot0 = x_0
    #pragma unroll
    for (int tt = 0; tt < 4; ++tt)
      accp[tt] = __builtin_amdgcn_mfma_f32_16x16x32_f16(ax, wb[tt][0], accp[tt], 0, 0, 0);
  }

  float4 xv = make_float4(0.f, 0.f, 0.f, 0.f);
  float c = 0.0f;

  // phase body: writes -> buf WR, reads -> buf RD (RD = 512 - WR)
  auto phase = [&](int p, int RD, int WR) {
    // issue bulk x loads (consumed at p%16==8; float across lgkm-only barriers)
    if (isx && (p & 15) == 0 && (p + 16 + xtr) < T_STEPS)
      xv = *(const float4*)(xsrc + (size_t)(p + 16 + xtr) * 32);

    if (ly == 0) {
      // ---- L1, step t=p ----
      if (p < T_STEPS) {
        const char* hb = hsbase + RD;
        const half8 a1 = *(const half8*)(hb);         // ks0: h1 lo
        const half8 a2 = *(const half8*)(hb + 128);   // ks1: h1 hi
        f32x4 acc[4];
        #pragma unroll
        for (int tt = 0; tt < 4; ++tt) {
          acc[tt] = __builtin_amdgcn_mfma_f32_16x16x32_f16(a1, wb[tt][1], accp[tt], 0, 0, 0);
          acc[tt] = __builtin_amdgcn_mfma_f32_16x16x32_f16(a2, wb[tt][2], acc[tt], 0, 0, 0);
        }
        // pre-issue x-ksteps for step p+1 BEFORE acts (fills pipe under act VALU)
        if (p + 1 < T_STEPS) {
          const int pn = p + 1;
          const half8 ax = *(const half8*)(xwbase + ((pn >> 4) & 1) * 2048 + (pn & 15) * 128);
          #pragma unroll
          for (int tt = 0; tt < 4; ++tt)
            accp[tt] = __builtin_amdgcn_mfma_f32_16x16x32_f16(ax, wb[tt][0],
                         (f32x4){bia[tt], bia[tt], bia[tt], bia[tt]}, 0, 0, 0);
        }
        if (l < 32) {
          const float gi = sigm2 (acc[0][0]);
          const float gf = sigm2 (acc[1][0]);
          const float gg = tanhg2(acc[2][0]);
          const float go = sigm2 (acc[3][0]);
          c = gf * c + gi * gg;
          const float hv = go * tanhc(c);
          *(_Float16*)((char*)hstate + WR + hwofs) = (_Float16)hv;   // h1_p
        }
      }
    } else {
      // ---- L2, finalize step t=p-2 (h1 ksteps already in accq) ----
      if (p >= 2) {
        const char* hb = hsbase + RD;
        const half8 a2lo = *(const half8*)(hb + 256);   // ks2: h2 lo
        const half8 a2hi = *(const half8*)(hb + 384);   // ks3: h2 hi
        f32x4 acc[4];
        #pragma unroll
        for (int tt = 0; tt < 4; ++tt) {
          acc[tt] = __builtin_amdgcn_mfma_f32_16x16x32_f16(a2lo, wb[tt][2], accq[tt], 0, 0, 0);
          acc[tt] = __builtin_amdgcn_mfma_f32_16x16x32_f16(a2hi, wb[tt][3], acc[tt], 0, 0, 0);
        }
        // mid-phase: read h1_{p-1} + issue h1-ksteps for step p-1 (before acts)
        if (p <= T_STEPS) {
          const half8 b1lo = *(const half8*)(hsbase + RD);         // ks0
          const half8 b1hi = *(const half8*)(hsbase + RD + 128);   // ks1
          #pragma unroll
          for (int tt = 0; tt < 4; ++tt) {
            accq[tt] = __builtin_amdgcn_mfma_f32_16x16x32_f16(b1lo, wb[tt][0],
                         (f32x4){bia[tt], bia[tt], bia[tt], bia[tt]}, 0, 0, 0);
            accq[tt] = __builtin_amdgcn_mfma_f32_16x16x32_f16(b1hi, wb[tt][1], accq[tt], 0, 0, 0);
          }
        }
        if (l < 32) {
          const float gi = sigm2 (acc[0][0]);
          const float gf = sigm2 (acc[1][0]);
          const float gg = tanhg2(acc[2][0]);
          const float go = sigm2 (acc[3][0]);
          c = gf * c + gi * gg;
          const float hv = go * tanhc(c);
          *(_Float16*)((char*)hstate + WR + hwofs) = (_Float16)hv;   // h2_{p-2}
          if (p == T_STEPS + 1) hfin[abm][u] = hv;                   // h2_{T-1}
        }
      } else if (p == 1) {
        // first accq issue: h1-ksteps for step 0 (h1_0 in buf RD)
        const half8 b1lo = *(const half8*)(hsbase + RD);
        const half8 b1hi = *(const half8*)(hsbase + RD + 128);
        #pragma unroll
        for (int tt = 0; tt < 4; ++tt) {
          accq[tt] = __builtin_amdgcn_mfma_f32_16x16x32_f16(b1lo, wb[tt][0],
                       (f32x4){bia[tt], bia[tt], bia[tt], bia[tt]}, 0, 0, 0);
          accq[tt] = __builtin_amdgcn_mfma_f32_16x16x32_f16(b1hi, wb[tt][1], accq[tt], 0, 0, 0);
        }
      }
    }

    // stage the register-held x window (loaded 8 phases ago)
    if (isx && (p & 15) == 8 && (p + 8 + xtr) < T_STEPS)
      *(half4*)((char*)xbig + (((p >> 4) + 1) & 1) * 2048 + xtr * 128 + xbm * 64 + xii * 8) = cvt4(xv);
  };

  // phases 0..T_STEPS+1 (L2 skew 2); even: read buf1/write buf0, odd: reverse
  for (int p2 = 0; p2 <= T_STEPS; p2 += 2) {
    phase(p2, 512, 0);
    barrier_lds();
    phase(p2 + 1, 0, 512);
    barrier_lds();
  }

  __syncthreads();   // full drain before epilogue

  // ---- head: y = LN(relu(hT@fc1^T+b1)@fc2^T+b2), 2 batch rows ----
  if (t < 256) {
    const int bi = t >> 7, j = t & 127;
    float a = fc1_b[j];
    const float4* w4 = (const float4*)(fc1_w + j * 64);
    const float4* h4 = (const float4*)hfin[bi];
    #pragma unroll
    for (int qq = 0; qq < 16; ++qq) {
      float4 wv = w4[qq]; float4 hv = h4[qq];
      a += wv.x * hv.x + wv.y * hv.y + wv.z * hv.z + wv.w * hv.w;
    }
    y1s[bi][j] = fmaxf(a, 0.0f);
  }
  __syncthreads();
  if (t < 256) {
    const int bi = t >> 7, j = t & 127;
    float a = fc2_b[j];
    const float4* w4 = (const float4*)(fc2_w + j * 128);
    const float4* y4 = (const float4*)y1s[bi];
    #pragma unroll
    for (int qq = 0; qq < 32; ++qq) {
      float4 wv = w4[qq]; float4 yv = y4[qq];
      a += wv.x * yv.x + wv.y * yv.y + wv.z * yv.z + wv.w * yv.w;
    }
    y2s[bi][j] = a;
  }
  __syncthreads();
  if (t < 128) {
    const int bi = t >> 6, jj = t & 63;
    float s  = y2s[bi][jj] + y2s[bi][64 + jj];
    float qs = y2s[bi][jj] * y2s[bi][jj] + y2s[bi][64 + jj] * y2s[bi][64 + jj];
    #pragma unroll
    for (int off = 32; off > 0; off >>= 1) {
      s  += __shfl_down(s, off, 64);
      qs += __shfl_down(qs, off, 64);
    }
    if (jj == 0) {
      const float mu  = s * (1.0f / 128.0f);
      const float var = qs * (1.0f / 128.0f) - mu * mu;
      redmu[bi] = mu;
      redrs[bi] = rsqrtf(var + 1e-5f);
    }
  }
  __syncthreads();
  if (t < 256) {
    const int bi = t >> 7, j = t & 127;
    out[(size_t)(2 * b + bi) * 128 + j] =
        (y2s[bi][j] - redmu[bi]) * redrs[bi] * ln_g[j] + ln_b[j];
  }
}

extern "C" void kernel_launch(void* const* d_in, const int* in_sizes, int n_in,
                              void* d_out, int out_size, void* d_ws, size_t ws_size,
                              hipStream_t stream) {
  const float* x     = (const float*)d_in[0];
  const float* w_ih1 = (const float*)d_in[1];
  const float* w_hh1 = (const float*)d_in[2];
  const float* b_ih1 = (const float*)d_in[3];
  const float* b_hh1 = (const float*)d_in[4];
  const float* w_ih2 = (const float*)d_in[5];
  const float* w_hh2 = (const float*)d_in[6];
  const float* b_ih2 = (const float*)d_in[7];
  const float* b_hh2 = (const float*)d_in[8];
  const float* fc1_w = (const float*)d_in[9];
  const float* fc1_b = (const float*)d_in[10];
  const float* fc2_w = (const float*)d_in[11];
  const float* fc2_b = (const float*)d_in[12];
  const float* ln_g  = (const float*)d_in[13];
  const float* ln_b  = (const float*)d_in[14];
  float* out = (float*)d_out;

  lstm_fused<<<NBLK, 512, 0, stream>>>(x, w_ih1, w_hh1, b_ih1, b_hh1,
                                       w_ih2, w_hh2, b_ih2, b_hh2,
                                       fc1_w, fc1_b, fc2_w, fc2_b,
                                       ln_g, ln_b, out);
}